// Round 3
// baseline (1275.359 us; speedup 1.0000x reference)
//
#include <hip/hip_runtime.h>
#include <hip/hip_bf16.h>

#define BATCH 400
#define NPATCH 196
#define DIM 384
#define RTRI 73920          // 384*385/2
#define NSUP 200
#define OUT_SCORE 0
#define OUT_ADC 125
#define OUT_CLS (125 + BATCH * RTRI)

// ws offsets in floats (total 602240 floats = 2.41 MB)
#define WS_W      0         // 400*196
#define WS_SQ     78400     // 400*384
#define WS_RSUM   232000    // 400*384 (atomic; zeroed each launch)
#define WS_RM     385600    // 400*384
#define WS_GM     539200    // 400
#define WS_QPART  539600    // 400*8
#define WS_DOTS   542800    // 200*200 (atomic; zeroed each launch)
#define WS_AD     582800    // 200*40
#define WS_QN     590800    // 200
#define WS_PN     591000    // 40
#define WS_PROTO  591040    // 25*384
#define WS_TSM    600640    // 25*64
#define WS_TOTAL  602240

__device__ __forceinline__ float wave_reduce(float v) {
    #pragma unroll
    for (int o = 32; o; o >>= 1) v += __shfl_down(v, o);
    return v;
}

__global__ void k_zero(float* __restrict__ p, int n) {
    int i = blockIdx.x * 256 + threadIdx.x;
    if (i < n) p[i] = 0.f;
}

// k1: cosine weights w, cls fp32 copy, sq[d] = diag of scaled Gram
__global__ __launch_bounds__(384) void k_prep(const float* __restrict__ lsn,
                                              float* __restrict__ ws,
                                              float* __restrict__ out) {
    int b = blockIdx.x, tid = threadIdx.x;
    __shared__ float clsL[DIM];
    __shared__ float wL[NPATCH];
    __shared__ float red[6];
    const float* base = lsn + (size_t)b * 197 * DIM;
    float c = base[tid];
    clsL[tid] = c;
    out[OUT_CLS + (size_t)b * DIM + tid] = c;
    float s = wave_reduce(c * c);
    int lane = tid & 63, wv = tid >> 6;
    if (!lane) red[wv] = s;
    __syncthreads();
    float clsn = fmaxf(sqrtf(red[0]+red[1]+red[2]+red[3]+red[4]+red[5]), 1e-8f);
    const float* patch = base + DIM;
    for (int p = wv; p < NPATCH; p += 6) {
        const float* pr = patch + p * DIM;
        float dot = 0.f, nsq = 0.f;
        #pragma unroll
        for (int t = 0; t < 6; t++) {
            float v = pr[lane + 64 * t];
            float cl = clsL[lane + 64 * t];
            dot = fmaf(v, cl, dot);
            nsq = fmaf(v, v, nsq);
        }
        dot = wave_reduce(dot);
        nsq = wave_reduce(nsq);
        if (!lane) {
            float val = dot / (clsn * fmaxf(sqrtf(nsq), 1e-8f));
            wL[p] = val;
            ws[WS_W + b * NPATCH + p] = val;
        }
    }
    __syncthreads();
    float acc = 0.f;
    for (int m = 0; m < NPATCH; m++) {
        float v = wL[m] * patch[m * DIM + tid];
        acc = fmaf(v, v, acc);
    }
    ws[WS_SQ + b * DIM + tid] = acc * (1.0f / 392.0f);
}

// k2: symmetric Gram tiles + pow(.,0.4) + triu fp32 write + atomic row sums
#define TK 28
__global__ __launch_bounds__(256) void k_gram(const float* __restrict__ lsn,
                                              float* __restrict__ ws,
                                              float* __restrict__ out) {
    int b = blockIdx.y;
    int t = blockIdx.x;
    int ti = 0;
    {
        int tt = t;
        while (tt >= 6 - ti) { tt -= 6 - ti; ++ti; }
        t = ti + tt;
    }
    int tj = t;
    __shared__ float As[TK][64];
    __shared__ float Bs[TK][64];
    __shared__ float redR[64];
    __shared__ float redC[64];
    int tid = threadIdx.x;
    int tx = tid & 15, ty = tid >> 4;
    const float* patch = lsn + (size_t)b * 197 * DIM + DIM;
    const float* wrow = ws + WS_W + b * NPATCH;
    float acc[4][4] = {};
    for (int k0 = 0; k0 < NPATCH; k0 += TK) {
        for (int l = tid; l < TK * 64; l += 256) {
            int mi = l >> 6, cc = l & 63;
            float wm = wrow[k0 + mi];
            const float* prow = patch + (size_t)(k0 + mi) * DIM;
            As[mi][cc] = wm * prow[ti * 64 + cc];
            Bs[mi][cc] = wm * prow[tj * 64 + cc];
        }
        __syncthreads();
        for (int kk = 0; kk < TK; kk++) {
            float4 a = *(const float4*)&As[kk][ty * 4];
            float4 bv = *(const float4*)&Bs[kk][tx * 4];
            float av[4] = {a.x, a.y, a.z, a.w};
            float bb[4] = {bv.x, bv.y, bv.z, bv.w};
            #pragma unroll
            for (int i = 0; i < 4; i++)
                #pragma unroll
                for (int j = 0; j < 4; j++)
                    acc[i][j] = fmaf(av[i], bb[j], acc[i][j]);
        }
        __syncthreads();
    }
    float sqi[4], sqj[4];
    #pragma unroll
    for (int i = 0; i < 4; i++) {
        sqi[i] = ws[WS_SQ + b * DIM + ti * 64 + ty * 4 + i];
        sqj[i] = ws[WS_SQ + b * DIM + tj * 64 + tx * 4 + i];
    }
    if (tid < 64) { redR[tid] = 0.f; redC[tid] = 0.f; }
    __syncthreads();
    float rsum[4] = {0,0,0,0}, csum[4] = {0,0,0,0};
    #pragma unroll
    for (int i = 0; i < 4; i++) {
        #pragma unroll
        for (int j = 0; j < 4; j++) {
            int gi = ti * 64 + ty * 4 + i;
            int gj = tj * 64 + tx * 4 + j;
            float dcov = sqi[i] + sqj[j] - acc[i][j] * (1.0f / 196.0f);
            dcov = fmaxf(dcov, 0.f) + 1e-5f;
            float val = __expf(0.4f * __logf(dcov));
            rsum[i] += val;
            csum[j] += val;
            if (gj >= gi) {
                int idx = gi * (769 - gi) / 2 + (gj - gi);
                out[OUT_ADC + (size_t)b * RTRI + idx] = val;
            }
        }
    }
    #pragma unroll
    for (int i = 0; i < 4; i++) {
        atomicAdd(&redR[ty * 4 + i], rsum[i]);
        atomicAdd(&redC[tx * 4 + i], csum[i]);
    }
    __syncthreads();
    if (tid < 64)
        atomicAdd(&ws[WS_RSUM + b * DIM + ti * 64 + tid], redR[tid]);
    if (ti != tj && tid >= 64 && tid < 128)
        atomicAdd(&ws[WS_RSUM + b * DIM + tj * 64 + (tid - 64)], redC[tid - 64]);
}

// k3: row means + grand mean
__global__ __launch_bounds__(384) void k_rowmean(float* __restrict__ ws) {
    int b = blockIdx.x, i = threadIdx.x;
    float s = ws[WS_RSUM + b * DIM + i];
    ws[WS_RM + b * DIM + i] = s * (1.0f / 384.0f);
    __shared__ float red[6];
    float tsum = wave_reduce(s);
    int lane = i & 63, wv = i >> 6;
    if (!lane) red[wv] = tsum;
    __syncthreads();
    if (i == 0) {
        float tot = red[0]+red[1]+red[2]+red[3]+red[4]+red[5];
        ws[WS_GM + b] = tot * (1.0f / (384.0f * 384.0f));
    }
}

// k4: in-place centering of adc (fp32) + per-row qnorm^2 partials
__global__ __launch_bounds__(256) void k_center(float* __restrict__ ws,
                                                float* __restrict__ out) {
    int split = blockIdx.x, b = blockIdx.y, tid = threadIdx.x;
    const float* rm = ws + WS_RM + b * DIM;
    float gm = ws[WS_GM + b];
    float* adc = out + OUT_ADC + (size_t)b * RTRI;
    float acc = 0.f;
    for (int c = tid; c < 2310; c += 256) {
        int e = split * 9240 + c * 4;
        float disc = 591361.0f - 8.0f * (float)e;
        int i = (int)((769.0f - sqrtf(disc)) * 0.5f);
        if (i < 0) i = 0;
        if (i > 383) i = 383;
        while (i > 0 && e < i * (769 - i) / 2) --i;
        while (e >= (i + 1) * (768 - i) / 2) ++i;
        int j = i + (e - i * (769 - i) / 2);
        #pragma unroll
        for (int u = 0; u < 4; u++) {
            float v = adc[e + u];
            float nv = v - rm[i] - rm[j] + gm;
            adc[e + u] = nv;
            acc = fmaf(nv, nv, acc);
            if (j == 383) { ++i; j = i; } else ++j;
        }
    }
    __shared__ float red[4];
    float tsum = wave_reduce(acc);
    if (!(tid & 63)) red[tid >> 6] = tsum;
    __syncthreads();
    if (!tid) ws[WS_QPART + b * 8 + split] = red[0] + red[1] + red[2] + red[3];
}

// k5: DOTS[r][c] = dot(query row r, ctx row c), split-K atomic
#define KCD 66
__global__ __launch_bounds__(320) void k_dots(const float* __restrict__ out,
                                              float* __restrict__ ws) {
    int rb = blockIdx.x;   // 0..24 -> 8 query rows each
    int cb = blockIdx.y;   // 0..4  -> 40 ctx cols each
    int ns = blockIdx.z;   // 0..7  -> 9240 K each
    int tid = threadIdx.x;
    int q = tid / 40, p = tid % 40;
    __shared__ float qs[8][KCD + 1];
    __shared__ float cs[40][KCD + 1];
    const float* adc = out + OUT_ADC;
    int r0 = rb * 8, c0 = cb * 40;
    int lo = ns * 9240;
    float acc = 0.f;
    for (int k0 = 0; k0 < 9240; k0 += KCD) {   // 140 chunks of 66
        for (int l = tid; l < 8 * KCD; l += 320) {
            int r = l / KCD, k = l % KCD;
            qs[r][k] = adc[(size_t)(NSUP + r0 + r) * RTRI + lo + k0 + k];
        }
        for (int l = tid; l < 40 * KCD; l += 320) {
            int r = l / KCD, k = l % KCD;
            cs[r][k] = adc[(size_t)(c0 + r) * RTRI + lo + k0 + k];
        }
        __syncthreads();
        #pragma unroll 6
        for (int k = 0; k < KCD; k++)
            acc = fmaf(qs[q][k], cs[p][k], acc);
        __syncthreads();
    }
    atomicAdd(&ws[WS_DOTS + (r0 + q) * 200 + c0 + p], acc);
}

// k5b: pn[c*8+f] = ||z_proto|| = sqrt(sum_{a,b} dot(ctx_a, ctx_b)) / 5
__global__ __launch_bounds__(256) void k_pn(const int* __restrict__ labels,
                                            const float* __restrict__ out,
                                            float* __restrict__ ws) {
    int o = blockIdx.x;      // c*8+f
    int c = o >> 3, f = o & 7;
    int tid = threadIdx.x;
    __shared__ int rows[5];
    if (tid == 0) {
        int cnt = 0;
        for (int s = 0; s < 25; s++)
            if (labels[s] == c && cnt < 5) rows[cnt++] = s * 8 + f;
    }
    __syncthreads();
    const float* adc = out + OUT_ADC;
    float acc[15] = {};
    for (int k = tid; k < RTRI; k += 256) {
        float v[5];
        #pragma unroll
        for (int a = 0; a < 5; a++) v[a] = adc[(size_t)rows[a] * RTRI + k];
        int idx = 0;
        #pragma unroll
        for (int a = 0; a < 5; a++)
            #pragma unroll
            for (int b2 = a; b2 < 5; b2++) {
                acc[idx] = fmaf(v[a], v[b2], acc[idx]);
                idx++;
            }
    }
    __shared__ float red[15];
    if (tid < 15) red[tid] = 0.f;
    __syncthreads();
    #pragma unroll
    for (int i = 0; i < 15; i++) {
        float t = wave_reduce(acc[i]);
        if (!(tid & 63)) atomicAdd(&red[i], t);
    }
    __syncthreads();
    if (tid == 0) {
        float tot = 0.f;
        int idx = 0;
        #pragma unroll
        for (int a = 0; a < 5; a++)
            #pragma unroll
            for (int b2 = a; b2 < 5; b2++) {
                tot += (a == b2) ? red[idx] : 2.f * red[idx];
                idx++;
            }
        ws[WS_PN + o] = fmaxf(sqrtf(fmaxf(tot, 0.f)) * 0.2f, 1e-8f);
    }
}

// k6: qn + ad from DOTS + QPART
__global__ __launch_bounds__(256) void k_post(const int* __restrict__ labels,
                                              float* __restrict__ ws) {
    __shared__ int mem[5][5];
    int tid = threadIdx.x;
    if (tid == 0) {
        int cnt[5] = {0,0,0,0,0};
        for (int s = 0; s < 25; s++) { int c = labels[s]; if (cnt[c] < 5) mem[c][cnt[c]++] = s; }
    }
    __syncthreads();
    for (int r = tid; r < 200; r += 256) {
        float ssum = 0.f;
        #pragma unroll
        for (int k = 0; k < 8; k++) ssum += ws[WS_QPART + (200 + r) * 8 + k];
        ws[WS_QN + r] = fmaxf(sqrtf(fmaxf(ssum, 0.f)), 1e-8f);
    }
    for (int idx = tid; idx < 8000; idx += 256) {
        int r = idx / 40, o = idx % 40;
        int c = o >> 3, f = o & 7;
        float s = 0.f;
        #pragma unroll
        for (int a = 0; a < 5; a++)
            s += ws[WS_DOTS + r * 200 + mem[c][a] * 8 + f];
        ws[WS_AD + idx] = s * 0.2f;
    }
}

// k7: proto[q] = mean_f(query cls) + mean_all(support cls)
__global__ __launch_bounds__(384) void k_proto(const float* __restrict__ lsn,
                                               float* __restrict__ ws) {
    int tid = threadIdx.x;
    float tsv = 0.f;
    for (int r = 0; r < 200; r++) tsv += lsn[(size_t)r * 197 * DIM + tid];
    tsv *= (1.0f / 200.0f);
    for (int q = 0; q < 25; q++) {
        float s = 0.f;
        #pragma unroll
        for (int f = 0; f < 8; f++) s += lsn[(size_t)(200 + q * 8 + f) * 197 * DIM + tid];
        ws[WS_PROTO + q * DIM + tid] = s * (1.0f / 8.0f) + tsv;
    }
}

// k8: tsm[q][g] = proto[q] . gen_weight[g]
__global__ __launch_bounds__(64) void k_tsm(const float* __restrict__ gw,
                                            float* __restrict__ ws) {
    int q = blockIdx.x, g = threadIdx.x;
    const float* pr = ws + WS_PROTO + q * DIM;
    const float* gr = gw + g * DIM;
    float s = 0.f;
    for (int d = 0; d < DIM; d++) s = fmaf(pr[d], gr[d], s);
    ws[WS_TSM + q * 64 + g] = s;
}

// k9: final score
__global__ __launch_bounds__(128) void k_score(const float* __restrict__ ws,
                                               float* __restrict__ out) {
    int t = threadIdx.x;
    if (t >= 125) return;
    int q = t / 5, wway = t % 5;
    float s = 0.f;
    for (int f = 0; f < 8; f++) {
        float qn = ws[WS_QN + q * 8 + f];
        for (int g = 0; g < 8; g++) {
            float ad = ws[WS_AD + (q * 8 + f) * 40 + wway * 8 + g];
            float pnv = ws[WS_PN + wway * 8 + g];
            s += (ad / (qn * pnv)) * ws[WS_TSM + q * 64 + f * 8 + g];
        }
    }
    out[OUT_SCORE + t] = s;
}

extern "C" void kernel_launch(void* const* d_in, const int* in_sizes, int n_in,
                              void* d_out, int out_size, void* d_ws, size_t ws_size,
                              hipStream_t stream) {
    const float* lsn = (const float*)d_in[0];
    const float* gw = (const float*)d_in[1];
    const int* labels = (const int*)d_in[2];
    float* ws = (float*)d_ws;
    float* out = (float*)d_out;

    // zero the atomic regions every launch (ws is never re-poisoned/zeroed by harness)
    {
        int n = (WS_AD - WS_RSUM);
        k_zero<<<dim3((n + 255) / 256), dim3(256), 0, stream>>>(ws + WS_RSUM, n);
    }
    k_prep<<<dim3(BATCH), dim3(384), 0, stream>>>(lsn, ws, out);
    k_gram<<<dim3(21, BATCH), dim3(256), 0, stream>>>(lsn, ws, out);
    k_rowmean<<<dim3(BATCH), dim3(384), 0, stream>>>(ws);
    k_center<<<dim3(8, BATCH), dim3(256), 0, stream>>>(ws, out);
    k_dots<<<dim3(25, 5, 8), dim3(320), 0, stream>>>(out, ws);
    k_pn<<<dim3(40), dim3(256), 0, stream>>>(labels, out, ws);
    k_post<<<1, dim3(256), 0, stream>>>(labels, ws);
    k_proto<<<1, dim3(384), 0, stream>>>(lsn, ws);
    k_tsm<<<dim3(25), dim3(64), 0, stream>>>(gw, ws);
    k_score<<<1, dim3(128), 0, stream>>>(ws, out);
}

// Round 4
// 793.778 us; speedup vs baseline: 1.6067x; 1.6067x over previous
//
#include <hip/hip_runtime.h>
#include <hip/hip_bf16.h>

#define BATCH 400
#define NPATCH 196
#define DIM 384
#define RTRI 73920          // 384*385/2
#define NSUP 200
#define OUT_SCORE 0
#define OUT_ADC 125
#define OUT_CLS (125 + BATCH * RTRI)

// ws offsets in floats (total 602240 floats = 2.41 MB)
#define WS_W      0         // 400*196
#define WS_SQ     78400     // 400*384
#define WS_RSUM   232000    // 400*384 (atomic; zeroed each launch)
#define WS_RM     385600    // 400*384
#define WS_GM     539200    // 400
#define WS_QPART  539600    // 400*8
#define WS_DOTS   542800    // 200*200 (atomic; zeroed each launch)
#define WS_AD     582800    // 200*40
#define WS_QN     590800    // 200
#define WS_PN     591000    // 40
#define WS_PROTO  591040    // 25*384
#define WS_TSM    600640    // 25*64
#define WS_TOTAL  602240

__device__ __forceinline__ float wave_reduce(float v) {
    #pragma unroll
    for (int o = 32; o; o >>= 1) v += __shfl_down(v, o);
    return v;
}

__global__ void k_zero(float* __restrict__ p, int n) {
    int i = blockIdx.x * 256 + threadIdx.x;
    if (i < n) p[i] = 0.f;
}

// k1: cosine weights w, cls fp32 copy, sq[d] = diag of scaled Gram
__global__ __launch_bounds__(384) void k_prep(const float* __restrict__ lsn,
                                              float* __restrict__ ws,
                                              float* __restrict__ out) {
    int b = blockIdx.x, tid = threadIdx.x;
    __shared__ float clsL[DIM];
    __shared__ float wL[NPATCH];
    __shared__ float red[6];
    const float* base = lsn + (size_t)b * 197 * DIM;
    float c = base[tid];
    clsL[tid] = c;
    out[OUT_CLS + (size_t)b * DIM + tid] = c;
    float s = wave_reduce(c * c);
    int lane = tid & 63, wv = tid >> 6;
    if (!lane) red[wv] = s;
    __syncthreads();
    float clsn = fmaxf(sqrtf(red[0]+red[1]+red[2]+red[3]+red[4]+red[5]), 1e-8f);
    const float* patch = base + DIM;
    for (int p = wv; p < NPATCH; p += 6) {
        const float* pr = patch + p * DIM;
        float dot = 0.f, nsq = 0.f;
        #pragma unroll
        for (int t = 0; t < 6; t++) {
            float v = pr[lane + 64 * t];
            float cl = clsL[lane + 64 * t];
            dot = fmaf(v, cl, dot);
            nsq = fmaf(v, v, nsq);
        }
        dot = wave_reduce(dot);
        nsq = wave_reduce(nsq);
        if (!lane) {
            float val = dot / (clsn * fmaxf(sqrtf(nsq), 1e-8f));
            wL[p] = val;
            ws[WS_W + b * NPATCH + p] = val;
        }
    }
    __syncthreads();
    float acc = 0.f;
    for (int m = 0; m < NPATCH; m++) {
        float v = wL[m] * patch[m * DIM + tid];
        acc = fmaf(v, v, acc);
    }
    ws[WS_SQ + b * DIM + tid] = acc * (1.0f / 392.0f);
}

// k2: symmetric Gram tiles + pow(.,0.4) + triu fp32 write + atomic row sums
#define TK 28
__global__ __launch_bounds__(256) void k_gram(const float* __restrict__ lsn,
                                              float* __restrict__ ws,
                                              float* __restrict__ out) {
    int b = blockIdx.y;
    int t = blockIdx.x;
    int ti = 0;
    {
        int tt = t;
        while (tt >= 6 - ti) { tt -= 6 - ti; ++ti; }
        t = ti + tt;
    }
    int tj = t;
    __shared__ float As[TK][64];
    __shared__ float Bs[TK][64];
    __shared__ float redR[64];
    __shared__ float redC[64];
    int tid = threadIdx.x;
    int tx = tid & 15, ty = tid >> 4;
    const float* patch = lsn + (size_t)b * 197 * DIM + DIM;
    const float* wrow = ws + WS_W + b * NPATCH;
    float acc[4][4] = {};
    for (int k0 = 0; k0 < NPATCH; k0 += TK) {
        for (int l = tid; l < TK * 64; l += 256) {
            int mi = l >> 6, cc = l & 63;
            float wm = wrow[k0 + mi];
            const float* prow = patch + (size_t)(k0 + mi) * DIM;
            As[mi][cc] = wm * prow[ti * 64 + cc];
            Bs[mi][cc] = wm * prow[tj * 64 + cc];
        }
        __syncthreads();
        for (int kk = 0; kk < TK; kk++) {
            float4 a = *(const float4*)&As[kk][ty * 4];
            float4 bv = *(const float4*)&Bs[kk][tx * 4];
            float av[4] = {a.x, a.y, a.z, a.w};
            float bb[4] = {bv.x, bv.y, bv.z, bv.w};
            #pragma unroll
            for (int i = 0; i < 4; i++)
                #pragma unroll
                for (int j = 0; j < 4; j++)
                    acc[i][j] = fmaf(av[i], bb[j], acc[i][j]);
        }
        __syncthreads();
    }
    float sqi[4], sqj[4];
    #pragma unroll
    for (int i = 0; i < 4; i++) {
        sqi[i] = ws[WS_SQ + b * DIM + ti * 64 + ty * 4 + i];
        sqj[i] = ws[WS_SQ + b * DIM + tj * 64 + tx * 4 + i];
    }
    if (tid < 64) { redR[tid] = 0.f; redC[tid] = 0.f; }
    __syncthreads();
    float rsum[4] = {0,0,0,0}, csum[4] = {0,0,0,0};
    #pragma unroll
    for (int i = 0; i < 4; i++) {
        #pragma unroll
        for (int j = 0; j < 4; j++) {
            int gi = ti * 64 + ty * 4 + i;
            int gj = tj * 64 + tx * 4 + j;
            float dcov = sqi[i] + sqj[j] - acc[i][j] * (1.0f / 196.0f);
            dcov = fmaxf(dcov, 0.f) + 1e-5f;
            float val = __expf(0.4f * __logf(dcov));
            rsum[i] += val;
            csum[j] += val;
            if (gj >= gi) {
                int idx = gi * (769 - gi) / 2 + (gj - gi);
                out[OUT_ADC + (size_t)b * RTRI + idx] = val;
            }
        }
    }
    #pragma unroll
    for (int i = 0; i < 4; i++) {
        atomicAdd(&redR[ty * 4 + i], rsum[i]);
        atomicAdd(&redC[tx * 4 + i], csum[i]);
    }
    __syncthreads();
    if (tid < 64)
        atomicAdd(&ws[WS_RSUM + b * DIM + ti * 64 + tid], redR[tid]);
    if (ti != tj && tid >= 64 && tid < 128)
        atomicAdd(&ws[WS_RSUM + b * DIM + tj * 64 + (tid - 64)], redC[tid - 64]);
}

// k3: row means + grand mean
__global__ __launch_bounds__(384) void k_rowmean(float* __restrict__ ws) {
    int b = blockIdx.x, i = threadIdx.x;
    float s = ws[WS_RSUM + b * DIM + i];
    ws[WS_RM + b * DIM + i] = s * (1.0f / 384.0f);
    __shared__ float red[6];
    float tsum = wave_reduce(s);
    int lane = i & 63, wv = i >> 6;
    if (!lane) red[wv] = tsum;
    __syncthreads();
    if (i == 0) {
        float tot = red[0]+red[1]+red[2]+red[3]+red[4]+red[5];
        ws[WS_GM + b] = tot * (1.0f / (384.0f * 384.0f));
    }
}

// k4: in-place centering of adc (fp32) + per-row qnorm^2 partials
__global__ __launch_bounds__(256) void k_center(float* __restrict__ ws,
                                                float* __restrict__ out) {
    int split = blockIdx.x, b = blockIdx.y, tid = threadIdx.x;
    const float* rm = ws + WS_RM + b * DIM;
    float gm = ws[WS_GM + b];
    float* adc = out + OUT_ADC + (size_t)b * RTRI;
    float acc = 0.f;
    for (int c = tid; c < 2310; c += 256) {
        int e = split * 9240 + c * 4;
        float disc = 591361.0f - 8.0f * (float)e;
        int i = (int)((769.0f - sqrtf(disc)) * 0.5f);
        if (i < 0) i = 0;
        if (i > 383) i = 383;
        while (i > 0 && e < i * (769 - i) / 2) --i;
        while (e >= (i + 1) * (768 - i) / 2) ++i;
        int j = i + (e - i * (769 - i) / 2);
        #pragma unroll
        for (int u = 0; u < 4; u++) {
            float v = adc[e + u];
            float nv = v - rm[i] - rm[j] + gm;
            adc[e + u] = nv;
            acc = fmaf(nv, nv, acc);
            if (j == 383) { ++i; j = i; } else ++j;
        }
    }
    __shared__ float red[4];
    float tsum = wave_reduce(acc);
    if (!(tid & 63)) red[tid >> 6] = tsum;
    __syncthreads();
    if (!tid) ws[WS_QPART + b * 8 + split] = red[0] + red[1] + red[2] + red[3];
}

// k5: DOTS[r][c] = dot(query row r, ctx row c). 40x40 tile, 1 wave, 5x5 microtile.
#define KCD 35
#define NSPL 96
#define KSL 770            // 73920 / 96
__global__ __launch_bounds__(64) void k_dots(const float* __restrict__ out,
                                             float* __restrict__ ws) {
    int rb = blockIdx.x;   // 0..4 -> 40 query rows
    int cb = blockIdx.y;   // 0..4 -> 40 ctx rows
    int ns = blockIdx.z;   // 0..95 -> K slice of 770
    int tid = threadIdx.x;
    int tx = tid & 7, ty = tid >> 3;
    __shared__ float qsT[KCD][41];   // k-major, stride 41 (41%32=9: conflict-free)
    __shared__ float csT[KCD][41];
    const float* adc = out + OUT_ADC;
    int lo = ns * KSL;
    const float* qbase = adc + (size_t)(NSUP + rb * 40) * RTRI + lo;
    const float* cbase = adc + (size_t)(cb * 40) * RTRI + lo;
    float acc[5][5] = {};
    for (int k0 = 0; k0 < KSL; k0 += KCD) {   // 22 chunks of 35
        for (int idx = tid; idx < 40 * KCD; idx += 64) {
            int r = idx / KCD, k = idx % KCD;   // consecutive tid -> consecutive k (coalesced runs)
            qsT[k][r] = qbase[(size_t)r * RTRI + k0 + k];
            csT[k][r] = cbase[(size_t)r * RTRI + k0 + k];
        }
        __syncthreads();
        #pragma unroll 5
        for (int k = 0; k < KCD; k++) {
            float qa[5], ca[5];
            #pragma unroll
            for (int i = 0; i < 5; i++) qa[i] = qsT[k][ty * 5 + i];
            #pragma unroll
            for (int j = 0; j < 5; j++) ca[j] = csT[k][tx * 5 + j];
            #pragma unroll
            for (int i = 0; i < 5; i++)
                #pragma unroll
                for (int j = 0; j < 5; j++)
                    acc[i][j] = fmaf(qa[i], ca[j], acc[i][j]);
        }
        __syncthreads();
    }
    #pragma unroll
    for (int i = 0; i < 5; i++)
        #pragma unroll
        for (int j = 0; j < 5; j++)
            atomicAdd(&ws[WS_DOTS + (rb * 40 + ty * 5 + i) * 200 + cb * 40 + tx * 5 + j],
                      acc[i][j]);
}

// k5b: pn[c*8+f] = ||z_proto|| = sqrt(sum_{a,b} dot(ctx_a, ctx_b)) / 5
__global__ __launch_bounds__(256) void k_pn(const int* __restrict__ labels,
                                            const float* __restrict__ out,
                                            float* __restrict__ ws) {
    int o = blockIdx.x;      // c*8+f
    int c = o >> 3, f = o & 7;
    int tid = threadIdx.x;
    __shared__ int rows[5];
    if (tid == 0) {
        int cnt = 0;
        for (int s = 0; s < 25; s++)
            if (labels[s] == c && cnt < 5) rows[cnt++] = s * 8 + f;
    }
    __syncthreads();
    const float* adc = out + OUT_ADC;
    float acc[15] = {};
    for (int k = tid; k < RTRI; k += 256) {
        float v[5];
        #pragma unroll
        for (int a = 0; a < 5; a++) v[a] = adc[(size_t)rows[a] * RTRI + k];
        int idx = 0;
        #pragma unroll
        for (int a = 0; a < 5; a++)
            #pragma unroll
            for (int b2 = a; b2 < 5; b2++) {
                acc[idx] = fmaf(v[a], v[b2], acc[idx]);
                idx++;
            }
    }
    __shared__ float red[15];
    if (tid < 15) red[tid] = 0.f;
    __syncthreads();
    #pragma unroll
    for (int i = 0; i < 15; i++) {
        float t = wave_reduce(acc[i]);
        if (!(tid & 63)) atomicAdd(&red[i], t);
    }
    __syncthreads();
    if (tid == 0) {
        float tot = 0.f;
        int idx = 0;
        #pragma unroll
        for (int a = 0; a < 5; a++)
            #pragma unroll
            for (int b2 = a; b2 < 5; b2++) {
                tot += (a == b2) ? red[idx] : 2.f * red[idx];
                idx++;
            }
        ws[WS_PN + o] = fmaxf(sqrtf(fmaxf(tot, 0.f)) * 0.2f, 1e-8f);
    }
}

// k6: qn + ad from DOTS + QPART
__global__ __launch_bounds__(256) void k_post(const int* __restrict__ labels,
                                              float* __restrict__ ws) {
    __shared__ int mem[5][5];
    int tid = threadIdx.x;
    if (tid == 0) {
        int cnt[5] = {0,0,0,0,0};
        for (int s = 0; s < 25; s++) { int c = labels[s]; if (cnt[c] < 5) mem[c][cnt[c]++] = s; }
    }
    __syncthreads();
    for (int r = tid; r < 200; r += 256) {
        float ssum = 0.f;
        #pragma unroll
        for (int k = 0; k < 8; k++) ssum += ws[WS_QPART + (200 + r) * 8 + k];
        ws[WS_QN + r] = fmaxf(sqrtf(fmaxf(ssum, 0.f)), 1e-8f);
    }
    for (int idx = tid; idx < 8000; idx += 256) {
        int r = idx / 40, o = idx % 40;
        int c = o >> 3, f = o & 7;
        float s = 0.f;
        #pragma unroll
        for (int a = 0; a < 5; a++)
            s += ws[WS_DOTS + r * 200 + mem[c][a] * 8 + f];
        ws[WS_AD + idx] = s * 0.2f;
    }
}

// k7: proto[q] = mean_f(query cls) + mean_all(support cls)
__global__ __launch_bounds__(384) void k_proto(const float* __restrict__ lsn,
                                               float* __restrict__ ws) {
    int tid = threadIdx.x;
    float tsv = 0.f;
    for (int r = 0; r < 200; r++) tsv += lsn[(size_t)r * 197 * DIM + tid];
    tsv *= (1.0f / 200.0f);
    for (int q = 0; q < 25; q++) {
        float s = 0.f;
        #pragma unroll
        for (int f = 0; f < 8; f++) s += lsn[(size_t)(200 + q * 8 + f) * 197 * DIM + tid];
        ws[WS_PROTO + q * DIM + tid] = s * (1.0f / 8.0f) + tsv;
    }
}

// k8: tsm[q][g] = proto[q] . gen_weight[g]
__global__ __launch_bounds__(64) void k_tsm(const float* __restrict__ gw,
                                            float* __restrict__ ws) {
    int q = blockIdx.x, g = threadIdx.x;
    const float* pr = ws + WS_PROTO + q * DIM;
    const float* gr = gw + g * DIM;
    float s = 0.f;
    for (int d = 0; d < DIM; d++) s = fmaf(pr[d], gr[d], s);
    ws[WS_TSM + q * 64 + g] = s;
}

// k9: final score
__global__ __launch_bounds__(128) void k_score(const float* __restrict__ ws,
                                               float* __restrict__ out) {
    int t = threadIdx.x;
    if (t >= 125) return;
    int q = t / 5, wway = t % 5;
    float s = 0.f;
    for (int f = 0; f < 8; f++) {
        float qn = ws[WS_QN + q * 8 + f];
        for (int g = 0; g < 8; g++) {
            float ad = ws[WS_AD + (q * 8 + f) * 40 + wway * 8 + g];
            float pnv = ws[WS_PN + wway * 8 + g];
            s += (ad / (qn * pnv)) * ws[WS_TSM + q * 64 + f * 8 + g];
        }
    }
    out[OUT_SCORE + t] = s;
}

extern "C" void kernel_launch(void* const* d_in, const int* in_sizes, int n_in,
                              void* d_out, int out_size, void* d_ws, size_t ws_size,
                              hipStream_t stream) {
    const float* lsn = (const float*)d_in[0];
    const float* gw = (const float*)d_in[1];
    const int* labels = (const int*)d_in[2];
    float* ws = (float*)d_ws;
    float* out = (float*)d_out;

    // zero the atomic regions every launch (ws is never re-poisoned/zeroed by harness)
    {
        int n = (WS_AD - WS_RSUM);
        k_zero<<<dim3((n + 255) / 256), dim3(256), 0, stream>>>(ws + WS_RSUM, n);
    }
    k_prep<<<dim3(BATCH), dim3(384), 0, stream>>>(lsn, ws, out);
    k_gram<<<dim3(21, BATCH), dim3(256), 0, stream>>>(lsn, ws, out);
    k_rowmean<<<dim3(BATCH), dim3(384), 0, stream>>>(ws);
    k_center<<<dim3(8, BATCH), dim3(256), 0, stream>>>(ws, out);
    k_dots<<<dim3(5, 5, NSPL), dim3(64), 0, stream>>>(out, ws);
    k_pn<<<dim3(40), dim3(256), 0, stream>>>(labels, out, ws);
    k_post<<<1, dim3(256), 0, stream>>>(labels, ws);
    k_proto<<<1, dim3(384), 0, stream>>>(lsn, ws);
    k_tsm<<<dim3(25), dim3(64), 0, stream>>>(gw, ws);
    k_score<<<1, dim3(128), 0, stream>>>(ws, out);
}